// Round 9
// baseline (39364.761 us; speedup 1.0000x reference)
//
#include <hip/hip_runtime.h>

typedef __bf16 bf16x8 __attribute__((ext_vector_type(8)));
typedef float f32x4 __attribute__((ext_vector_type(4)));
typedef unsigned short u16;
typedef unsigned int u32;

#define MFMA16(a, b, c) __builtin_amdgcn_mfma_f32_16x16x32_bf16((a), (b), (c), 0, 0, 0)

// ---------------------------------------------------------------------------
// Grid 256 = 8 groups x 32 blocks (2 sets x 16). Group g owns batch rows
// g*16..g*16+15 (row-separable DAG). Per-group sync: flat 32-participant
// AGENT/LLC epoch counter (proven replay-safe class). States: sc0sc1 LLC ops
// (round-4/8-proven). Weights: plain cached reads after sc1 init + one-time
// wbl2/inv hygiene (proven). Bounded polls everywhere.
//
// Per step (5 barriers): A: set0 s0<-W0@[x|h]. B: set0 s1 (reg rs1).
// C: set0 s2(store,reg)+s4(reg only, shared A-read); set1 s3(store).
// D: set0 s5(store,reg) then s7(reg only). E: set0 s6,s8(reg) + mean from
// regs + one s3 slice read -> out, h. s4/s7 never touch memory.
//
// counters (u32 idx; 8192 B memset 0): global barrier 512; group g 1024+g*64.
// ws u16: Wh[5242880] @ byte 8192, Wl[5242880], T[8][6][16384]
//   slots: 0=h 1=s0 2=s1 3=s2 4=s3 5=s5 (hi-plane[8192] ++ lo-plane[8192])
// ---------------------------------------------------------------------------

__device__ __forceinline__ u16 f2bf(float f) {
  u32 u = __float_as_uint(f);
  u += 0x7FFFu + ((u >> 16) & 1u);
  return (u16)(u >> 16);
}
__device__ __forceinline__ float bf2f(u32 h) { return __uint_as_float(h << 16); }
__device__ __forceinline__ void splitbf(float f, u16 &hi, u16 &lo) {
  hi = f2bf(f);
  lo = f2bf(f - bf2f((u32)hi));
}

__device__ __forceinline__ void issue_ld128_sc(bf16x8 &d, const u16 *p) {
  asm volatile("global_load_dwordx4 %0, %1, off sc0 sc1" : "=v"(d) : "v"(p));
}
__device__ __forceinline__ void issue_ldu16_sc(u32 &d, const u16 *p) {
  asm volatile("global_load_ushort %0, %1, off sc0 sc1" : "=v"(d) : "v"(p));
}
__device__ __forceinline__ void wait_vm() {
  asm volatile("s_waitcnt vmcnt(0)" ::: "memory");
  __builtin_amdgcn_sched_barrier(0);
}
__device__ __forceinline__ void st16_sc(u16 *p, u16 v) {
  u32 q = v;
  asm volatile("global_store_short %0, %1, off sc0 sc1" :: "v"(p), "v"(q) : "memory");
}

__device__ __forceinline__ int mbase(int m) {          // u16 elems; m=0 -> W0 (K=1024)
  return m == 0 ? 0 : 1048576 + (m - 1) * 524288;
}
__device__ __forceinline__ int lineOf(int row, int scol) {
  return (scol >> 5) * 64 + row + ((scol >> 3) & 3) * 16;
}
__device__ __forceinline__ int goffG(int slot, int row, int scol) {  // hi; lo at +8192
  return slot * 16384 + lineOf(row, scol) * 8 + (scol & 7);
}

template <int A> __device__ __forceinline__ float actf(float x) {
  if (A == 0) { float e = __expf(2.f * x); return 1.f - 2.f / (e + 1.f); } // tanh
  if (A == 1) return 1.f / (1.f + __expf(-x));                            // sigmoid
  if (A == 2) return fmaxf(x, 0.f);                                       // relu
  return x;                                                               // identity
}

template <int ACT, bool STORE>
__device__ __forceinline__ void act2(f32x4 acc, const float *spv, u16 *Sg, int dslot,
                                     int cb, int l4, int l15, float *sv) {
#pragma unroll
  for (int j = 0; j < 4; ++j) {
    float cp = acc[j];
    float hp = __shfl_xor(cp, 1);
    float sig = 1.f / (1.f + __expf(-cp));
    float sval = spv[j] + sig * (actf<ACT>(hp) - spv[j]);
    sv[j] = sval;
    if (STORE && ((l15 & 1) == 0)) {
      int row = l4 * 4 + j, scol = cb * 8 + (l15 >> 1);
      u16 hi, lo; splitbf(sval, hi, lo);
      u16 *p = Sg + goffG(dslot, row, scol);
      st16_sc(p, hi);
      st16_sc(p + 8192, lo);
    }
  }
}

// K=512 GEMM; A-frags + s_prev read directly from LLC panel (one wait);
// weights plain cached loads. Per-output store flags; sv always returned.
template <int ACT0, int ACT1, bool TWO, bool ST0, bool ST1>
__device__ __forceinline__ void gemmD(const u16 *Wh, const u16 *Wl, u16 *Sg,
                                      int aslot, int m0, int m1, int d0, int d1,
                                      int cb, int ln, int l4, int l15,
                                      float *sv0, float *sv1) {
  const int scol = cb * 8 + (l15 >> 1);
  u32 sph[4], spl[4];
#pragma unroll
  for (int j = 0; j < 4; ++j) {
    const u16 *p = Sg + goffG(aslot, l4 * 4 + j, scol);
    issue_ldu16_sc(sph[j], p);
    issue_ldu16_sc(spl[j], p + 8192);
  }
  bf16x8 Ah[16], Al[16];
#pragma unroll
  for (int kc = 0; kc < 16; ++kc) {
    const u16 *ap = Sg + aslot * 16384 + (kc * 64 + ln) * 8;
    issue_ld128_sc(Ah[kc], ap);
    issue_ld128_sc(Al[kc], ap + 8192);
  }
  wait_vm();
  f32x4 acc0 = {0.f, 0.f, 0.f, 0.f}, acc1 = {0.f, 0.f, 0.f, 0.f};
  const u16 *w0h = Wh + mbase(m0) + (cb * 16 * 64 + ln) * 8;
  const u16 *w0l = Wl + mbase(m0) + (cb * 16 * 64 + ln) * 8;
  const u16 *w1h = Wh + mbase(m1) + (cb * 16 * 64 + ln) * 8;
  const u16 *w1l = Wl + mbase(m1) + (cb * 16 * 64 + ln) * 8;
#pragma unroll
  for (int kc = 0; kc < 16; ++kc) {
    bf16x8 b0h = *(const bf16x8 *)(w0h + kc * 512);
    bf16x8 b0l = *(const bf16x8 *)(w0l + kc * 512);
    acc0 = MFMA16(Ah[kc], b0h, acc0);
    acc0 = MFMA16(Ah[kc], b0l, acc0);
    acc0 = MFMA16(Al[kc], b0h, acc0);
    if (TWO) {
      bf16x8 b1h = *(const bf16x8 *)(w1h + kc * 512);
      bf16x8 b1l = *(const bf16x8 *)(w1l + kc * 512);
      acc1 = MFMA16(Ah[kc], b1h, acc1);
      acc1 = MFMA16(Ah[kc], b1l, acc1);
      acc1 = MFMA16(Al[kc], b1h, acc1);
    }
  }
  float spv[4];
#pragma unroll
  for (int j = 0; j < 4; ++j) spv[j] = bf2f(sph[j]) + bf2f(spl[j]);
  act2<ACT0, ST0>(acc0, spv, Sg, d0, cb, l4, l15, sv0);
  if (TWO) act2<ACT1, ST1>(acc1, spv, Sg, d1, cb, l4, l15, sv1);
}

// round A: s0 = h + sigmoid(c)*(tanh(h') - h); A = [x_t | h], K=1024, W0.
// h-frags + spv via one LLC wait; x read directly (plain cached), split on fly.
__device__ __forceinline__ void roundA(const float *xin, int t, int trow0,
                                       const u16 *Wh, const u16 *Wl, u16 *Sg,
                                       int cb, int ln, int l4, int l15) {
  const int scol = cb * 8 + (l15 >> 1);
  u32 sph[4], spl[4];
#pragma unroll
  for (int j = 0; j < 4; ++j) {
    const u16 *p = Sg + goffG(0, l4 * 4 + j, scol);
    issue_ldu16_sc(sph[j], p);
    issue_ldu16_sc(spl[j], p + 8192);
  }
  bf16x8 Ah[16], Al[16];
#pragma unroll
  for (int kc = 0; kc < 16; ++kc) {
    const u16 *ap = Sg + (kc * 64 + ln) * 8;  // slot 0 = h
    issue_ld128_sc(Ah[kc], ap);
    issue_ld128_sc(Al[kc], ap + 8192);
  }
  wait_vm();
  f32x4 acc = {0.f, 0.f, 0.f, 0.f};
  const u16 *wh = Wh + (cb * 32 * 64 + ln) * 8;
  const u16 *wl = Wl + (cb * 32 * 64 + ln) * 8;
  const float *xp = xin + (t * 128 + trow0 + l15) * 512 + l4 * 8;
#pragma unroll
  for (int kc = 0; kc < 16; ++kc) {  // x half (k<512)
    f32x4 xa = *(const f32x4 *)(xp + kc * 32);
    f32x4 xb = *(const f32x4 *)(xp + kc * 32 + 4);
    union { u16 u[8]; bf16x8 v; } H, Lo;
#pragma unroll
    for (int e = 0; e < 4; ++e) {
      splitbf(xa[e], H.u[e], Lo.u[e]);
      splitbf(xb[e], H.u[4 + e], Lo.u[4 + e]);
    }
    bf16x8 bh = *(const bf16x8 *)(wh + kc * 512);
    bf16x8 bl = *(const bf16x8 *)(wl + kc * 512);
    acc = MFMA16(H.v, bh, acc);
    acc = MFMA16(H.v, bl, acc);
    acc = MFMA16(Lo.v, bh, acc);
  }
#pragma unroll
  for (int kc = 0; kc < 16; ++kc) {  // h half (k>=512)
    bf16x8 bh = *(const bf16x8 *)(wh + (16 + kc) * 512);
    bf16x8 bl = *(const bf16x8 *)(wl + (16 + kc) * 512);
    acc = MFMA16(Ah[kc], bh, acc);
    acc = MFMA16(Ah[kc], bl, acc);
    acc = MFMA16(Al[kc], bh, acc);
  }
  float spv[4];
#pragma unroll
  for (int j = 0; j < 4; ++j) spv[j] = bf2f(sph[j]) + bf2f(spl[j]);
  float sv[4];
  act2<0, true>(acc, spv, Sg, 1, cb, l4, l15, sv);
}

// global flat epoch barrier over 256 blocks (AGENT counter, bounded poll)
__device__ __forceinline__ void gflat(u32 *cnt, u32 &ep, u32 &pb) {
  wait_vm();
  __syncthreads();
  ep += 256u;
  if (threadIdx.x == 0) {
    __hip_atomic_fetch_add(&cnt[512], 1u, __ATOMIC_RELAXED, __HIP_MEMORY_SCOPE_AGENT);
    bool ok = false;
    for (u32 i = 0; i < pb; ++i) {
      u32 v = __hip_atomic_load(&cnt[512], __ATOMIC_RELAXED, __HIP_MEMORY_SCOPE_AGENT);
      if ((int)(v - ep) >= 0) { ok = true; break; }
      __builtin_amdgcn_s_sleep(2);
    }
    if (!ok) pb = 4096u;
  }
  __syncthreads();
}

// per-group epoch barrier: 32 participants, flat AGENT counter, bounded poll
__device__ __forceinline__ void grbar(u32 *gc, u32 &tep, u32 &pb) {
  wait_vm();
  __syncthreads();
  tep += 32u;
  if (threadIdx.x == 0) {
    __hip_atomic_fetch_add(gc, 1u, __ATOMIC_RELAXED, __HIP_MEMORY_SCOPE_AGENT);
    bool ok = false;
    for (u32 i = 0; i < pb; ++i) {
      u32 v = __hip_atomic_load(gc, __ATOMIC_RELAXED, __HIP_MEMORY_SCOPE_AGENT);
      if ((int)(v - tep) >= 0) { ok = true; break; }
      __builtin_amdgcn_s_sleep(2);
    }
    if (!ok) pb = 4096u;
  }
  __syncthreads();
}

__global__ __launch_bounds__(256, 1) void darts_rnn(
    const float *__restrict__ xin, const float *__restrict__ h0in,
    const float *__restrict__ W0, const float *__restrict__ Wsi,
    float *__restrict__ out, u16 *__restrict__ wsu) {
  u32 *cnt = (u32 *)wsu;
  u16 *Wh = wsu + 4096;            // byte 8192
  u16 *Wl = Wh + 5242880;
  u16 *Tbase = Wl + 5242880;

  const int tid = threadIdx.x, bid = blockIdx.x;
  const int ln = tid & 63, wid = tid >> 6;
  const int l15 = ln & 15, l4 = ln >> 4;
  const int g = bid >> 5;                   // group 0..7 (32 blocks)
  const int set = (bid >> 4) & 1;           // 2 sets x 16 blocks
  const int cb = (bid & 15) * 4 + wid;      // column tile 0..63
  const int trow0 = g * 16;
  u16 *Sg = Tbase + g * 98304;              // 6 slots x 16384
  u32 *gc = cnt + 1024 + g * 64;

  u32 ep = 0, pb = 1u << 24;

  // ---- hygiene: write back dirty ws lines, then invalidate L2 (proven) ----
  if (wid == 0) asm volatile("buffer_wbl2 sc1" ::: "memory");
  wait_vm();
  gflat(cnt, ep, pb);
  if (wid == 0) asm volatile("buffer_inv sc1" ::: "memory");
  wait_vm();
  gflat(cnt, ep, pb);

  // ---- P0: weight hi/lo split into fragment layout (sc1 stores, LLC) ----
  for (int idx = bid * 256 + tid; idx < 5242880; idx += 65536) {
    int mk = idx >> 10, oc = idx & 1023;
    int m, k;
    if (mk < 1024) { m = 0; k = mk; } else { m = 1 + ((mk - 1024) >> 9); k = (mk - 1024) & 511; }
    float v = (m == 0) ? W0[k * 1024 + oc] : Wsi[((m - 1) * 512 + k) * 1024 + oc];
    int colp = (oc < 512) ? (oc * 2) : ((oc - 512) * 2 + 1);  // interleave c,h cols
    int cbw = colp >> 4;
    int kc = k >> 5;
    int lnn = (colp & 15) + ((k >> 3) & 3) * 16;
    int el = k & 7;
    int lineBase = (m == 0) ? (cbw * 32 + kc) : (cbw * 16 + kc);  // W0: K=1024
    int e = mbase(m) + (lineBase * 64 + lnn) * 8 + el;
    u16 hi, lo; splitbf(v, hi, lo);
    st16_sc(Wh + e, hi);
    st16_sc(Wl + e, lo);
  }
  // ---- h0 -> group slot 0 (redundant across members, benign) ----
  for (int i = tid; i < 8192; i += 256) {
    int row = i >> 9, k = i & 511;
    u16 hi, lo;
    splitbf(h0in[(trow0 + row) * 512 + k], hi, lo);
    u16 *p = Sg + goffG(0, row, k);
    st16_sc(p, hi);
    st16_sc(p + 8192, lo);
  }
  gflat(cnt, ep, pb);   // weights + all group panels ready

  u32 tep = 0;
  for (int t = 0; t < 256; ++t) {
    float rs1[4], rs2[4], rs4[4], rs5[4], rs7[4], dum[4];
    // ---- round A: set0: s0 <- W0 @ [x_t | h] -> slot1 ----
    if (set == 0) roundA(xin, t, trow0, Wh, Wl, Sg, cb, ln, l4, l15);
    grbar(gc, tep, pb);
    // ---- round B: set0: s1 <- Ws0(sig) on s0 -> slot2, reg rs1 ----
    if (set == 0)
      gemmD<1, 1, false, true, true>(Wh, Wl, Sg, 1, 1, 1, 2, 2, cb, ln, l4, l15, rs1, dum);
    grbar(gc, tep, pb);
    // ---- round C: set0: s2(relu)->slot3+reg, s4(ident) reg-only (shared A);
    //               set1: s3(relu)->slot4 ----
    if (set == 0)
      gemmD<2, 3, true, true, false>(Wh, Wl, Sg, 2, 2, 4, 3, 0, cb, ln, l4, l15, rs2, rs4);
    else
      gemmD<2, 2, false, true, true>(Wh, Wl, Sg, 2, 3, 3, 4, 4, cb, ln, l4, l15, dum, dum);
    grbar(gc, tep, pb);
    // ---- round D: set0: s5(tanh) on s2 -> slot5+reg; s7(tanh) on s3 reg-only ----
    if (set == 0) {
      gemmD<0, 0, false, true, true>(Wh, Wl, Sg, 3, 5, 5, 5, 5, cb, ln, l4, l15, rs5, dum);
      gemmD<0, 0, false, false, false>(Wh, Wl, Sg, 4, 7, 7, 0, 0, cb, ln, l4, l15, rs7, dum);
    }
    grbar(gc, tep, pb);
    // ---- round E: set0: s6(sig), s8(relu) on s5 (reg); mean -> out, h ----
    if (set == 0) {
      float sv6[4], sv8[4];
      gemmD<1, 2, true, false, false>(Wh, Wl, Sg, 5, 6, 8, 0, 0, cb, ln, l4, l15, sv6, sv8);
      const int scol = cb * 8 + (l15 >> 1);
      u32 s3h[4], s3l[4];
#pragma unroll
      for (int j = 0; j < 4; ++j) {
        const u16 *p = Sg + goffG(4, l4 * 4 + j, scol);
        issue_ldu16_sc(s3h[j], p);
        issue_ldu16_sc(s3l[j], p + 8192);
      }
      wait_vm();
      if ((l15 & 1) == 0) {
#pragma unroll
        for (int j = 0; j < 4; ++j) {
          float s3v = bf2f(s3h[j]) + bf2f(s3l[j]);
          float sum = rs1[j] + rs2[j] + rs4[j] + rs5[j] + rs7[j] + sv6[j] + sv8[j] + s3v;
          float hnew = sum * 0.125f;
          int row = l4 * 4 + j;
          out[t * 65536 + (trow0 + row) * 512 + scol] = hnew;
          if (t == 255) out[16777216 + (trow0 + row) * 512 + scol] = hnew;
          u16 hi, lo; splitbf(hnew, hi, lo);
          u16 *p = Sg + goffG(0, row, scol);
          st16_sc(p, hi);
          st16_sc(p + 8192, lo);
        }
      }
    }
    grbar(gc, tep, pb);
  }
}

extern "C" void kernel_launch(void *const *d_in, const int *in_sizes, int n_in,
                              void *d_out, int out_size, void *d_ws, size_t ws_size,
                              hipStream_t stream) {
  const float *x = (const float *)d_in[0];
  const float *h0 = (const float *)d_in[1];
  const float *W0 = (const float *)d_in[2];
  const float *Ws = (const float *)d_in[3];
  float *out = (float *)d_out;
  u16 *ws = (u16 *)d_ws;

  hipMemsetAsync(d_ws, 0, 8192, stream);  // zero counters

  void *args[] = {(void *)&x, (void *)&h0, (void *)&W0, (void *)&Ws, (void *)&out, (void *)&ws};
  hipError_t err = hipLaunchCooperativeKernel((void *)darts_rnn, dim3(256), dim3(256),
                                              args, 0, stream);
  if (err != hipSuccess) {
    (void)hipGetLastError();
    darts_rnn<<<dim3(256), dim3(256), 0, stream>>>(x, h0, W0, Ws, out, ws);
  }
}

// Round 10
// 22006.424 us; speedup vs baseline: 1.7888x; 1.7888x over previous
//
#include <hip/hip_runtime.h>

typedef __bf16 bf16x8 __attribute__((ext_vector_type(8)));
typedef float f32x4 __attribute__((ext_vector_type(4)));
typedef unsigned short u16;
typedef unsigned int u32;
typedef u16 u16x8 __attribute__((ext_vector_type(8)));

#define MFMA16(a, b, c) __builtin_amdgcn_mfma_f32_16x16x32_bf16((a), (b), (c), 0, 0, 0)

// ---------------------------------------------------------------------------
// Round-4 structure (proven 24.65ms) + vectorized state traffic + reg-carry.
// Grid 256x256: bid<128 = half0 (rt=bid>>4, cb=(bid&15)*4+wid), bid>=128 same.
// States: sc0sc1 LLC ops, now 16B-vectorized via per-wave LDS transpose.
// Weights: plain cached reads after sc1 init + one-time wbl2/inv hygiene.
// Barrier: hierarchical AGENT epoch counters (memset-zeroed, bounded polls).
//
// Per step (5 barriers):
//  A: half0 s0=f(W0@[x|h]) -> slot1            (vec store)
//  B: half0 s1 (sig)       -> slot2, reg rs1   (vec store)
//  C: half0 s2(relu)->slot3+rs2, s4(ident) reg-only; half1 s3(relu)->slot4
//  D: half0 s5(tanh on s2)->slot5+rs5;          half1 s7(tanh on s3)->slot6
//  E: half0 s6(sig),s8(relu) reg; mean(rs*,s3,s7 vec-read) -> out, h->slot0
//
// counters (4096B memset 0): gbar sub c*64 (c<8), top 512.
// ws u16: Wh[5242880] @ byte 4096*2? -> Wh = wsu+2048 (byte 4096), Wl next,
//   S[7][131072]: slots 0=h 1=s0 2=s1 3=s2 4=s3 5=s5 6=s7 (128x512 panels,
//   per (slot,rt): hi-plane[8192] ++ lo-plane[8192]).
// ---------------------------------------------------------------------------

__device__ __forceinline__ u16 f2bf(float f) {
  u32 u = __float_as_uint(f);
  u += 0x7FFFu + ((u >> 16) & 1u);
  return (u16)(u >> 16);
}
__device__ __forceinline__ float bf2f(u32 h) { return __uint_as_float(h << 16); }
__device__ __forceinline__ void splitbf(float f, u16 &hi, u16 &lo) {
  hi = f2bf(f);
  lo = f2bf(f - bf2f((u32)hi));
}

__device__ __forceinline__ void issue_ld128_sc(bf16x8 &d, const u16 *p) {
  asm volatile("global_load_dwordx4 %0, %1, off sc0 sc1" : "=v"(d) : "v"(p));
}
__device__ __forceinline__ void issue_ld128u_sc(u16x8 &d, const u16 *p) {
  asm volatile("global_load_dwordx4 %0, %1, off sc0 sc1" : "=v"(d) : "v"(p));
}
__device__ __forceinline__ void st128_sc(u16 *p, u16x8 v) {
  asm volatile("global_store_dwordx4 %0, %1, off sc0 sc1" :: "v"(p), "v"(v) : "memory");
}
__device__ __forceinline__ void st16_sc(u16 *p, u16 v) {
  u32 q = v;
  asm volatile("global_store_short %0, %1, off sc0 sc1" :: "v"(p), "v"(q) : "memory");
}
__device__ __forceinline__ void wait_vm() {
  asm volatile("s_waitcnt vmcnt(0)" ::: "memory");
  __builtin_amdgcn_sched_barrier(0);
}

__device__ __forceinline__ int mbase(int m) {          // u16 elems; m=0 -> W0 (K=1024)
  return m == 0 ? 0 : 1048576 + (m - 1) * 524288;
}
__device__ __forceinline__ int lineOf(int row15, int scol) {
  return (scol >> 5) * 64 + row15 + ((scol >> 3) & 3) * 16;
}
__device__ __forceinline__ int goff(int slot, int row, int scol) {  // hi; lo at +8192
  return slot * 131072 + (row >> 4) * 16384 + lineOf(row & 15, scol) * 8 + (scol & 7);
}

template <int A> __device__ __forceinline__ float actf(float x) {
  if (A == 0) { float e = __expf(2.f * x); return 1.f - 2.f / (e + 1.f); } // tanh
  if (A == 1) return 1.f / (1.f + __expf(-x));                            // sigmoid
  if (A == 2) return fmaxf(x, 0.f);                                       // relu
  return x;                                                               // identity
}

__device__ __forceinline__ float lds_elem(const u16 *lds, int row15, int scol) {
  int o = lineOf(row15, scol) * 8 + (scol & 7);
  return bf2f(lds[o]) + bf2f(lds[o + 8192]);
}

// copy one (slot,rt) 32KB panel global->LDS (layouts identical)
__device__ __forceinline__ void stage_panel(const u16 *S, int slot, int rt, u16 *lds, int tid) {
  const u16 *src = S + slot * 131072 + rt * 16384 + tid * 8;
  bf16x8 r[8];
#pragma unroll
  for (int i = 0; i < 8; ++i) issue_ld128_sc(r[i], src + i * 2048);
  wait_vm();
#pragma unroll
  for (int i = 0; i < 8; ++i) *(bf16x8 *)(lds + tid * 8 + i * 2048) = r[i];
}

// activation only (no store): sval[j] for this lane's (row=l4*4+j, scol)
template <int ACT>
__device__ __forceinline__ void act_only(f32x4 acc, const float *spv, float *sv) {
#pragma unroll
  for (int j = 0; j < 4; ++j) {
    float cp = acc[j];
    float hp = __shfl_xor(cp, 1);
    float sig = 1.f / (1.f + __expf(-cp));
    sv[j] = spv[j] + sig * (actf<ACT>(hp) - spv[j]);
  }
}

// vectorized state store: frag-layout sv -> per-wave LDS transpose -> 2x16B/row
__device__ __forceinline__ void store_state(const float *sv, u16 *S, int dslot,
                                            int rt, int cb, float *fscrw,
                                            int ln, int l4, int l15) {
  if ((l15 & 1) == 0) {
#pragma unroll
    for (int j = 0; j < 4; ++j) fscrw[(l4 * 4 + j) * 8 + (l15 >> 1)] = sv[j];
  }
  // intra-wave LDS dependency; compiler inserts lgkmcnt waits
  if (ln < 16) {
    u16x8 H, L;
#pragma unroll
    for (int c = 0; c < 8; ++c) {
      u16 hi, lo;
      splitbf(fscrw[ln * 8 + c], hi, lo);
      H[c] = hi; L[c] = lo;
    }
    u16 *p = S + goff(dslot, rt * 16 + ln, cb * 8);
    st128_sc(p, H);
    st128_sc(p + 8192, L);
  }
}

// K=512 GEMM; A-panel + s_prev from LDS; weights plain cached loads; no store
template <int ACT0, int ACT1, bool TWO>
__device__ __forceinline__ void gemm512(const u16 *Wh, const u16 *Wl, const u16 *lds,
                                        int m0, int m1, int cb, int ln, int l4, int l15,
                                        float *sv0, float *sv1) {
  float spv[4];
#pragma unroll
  for (int j = 0; j < 4; ++j) spv[j] = lds_elem(lds, l4 * 4 + j, cb * 8 + (l15 >> 1));
  f32x4 acc0 = {0.f, 0.f, 0.f, 0.f}, acc1 = {0.f, 0.f, 0.f, 0.f};
  const u16 *w0h = Wh + mbase(m0) + (cb * 16 * 64 + ln) * 8;
  const u16 *w0l = Wl + mbase(m0) + (cb * 16 * 64 + ln) * 8;
  const u16 *w1h = Wh + mbase(m1) + (cb * 16 * 64 + ln) * 8;
  const u16 *w1l = Wl + mbase(m1) + (cb * 16 * 64 + ln) * 8;
#pragma unroll
  for (int kc = 0; kc < 16; ++kc) {
    bf16x8 Ah = *(const bf16x8 *)(lds + (kc * 64 + ln) * 8);
    bf16x8 Al = *(const bf16x8 *)(lds + 8192 + (kc * 64 + ln) * 8);
    bf16x8 b0h = *(const bf16x8 *)(w0h + kc * 512);
    bf16x8 b0l = *(const bf16x8 *)(w0l + kc * 512);
    acc0 = MFMA16(Ah, b0h, acc0);
    acc0 = MFMA16(Ah, b0l, acc0);
    acc0 = MFMA16(Al, b0h, acc0);
    if (TWO) {
      bf16x8 b1h = *(const bf16x8 *)(w1h + kc * 512);
      bf16x8 b1l = *(const bf16x8 *)(w1l + kc * 512);
      acc1 = MFMA16(Ah, b1h, acc1);
      acc1 = MFMA16(Ah, b1l, acc1);
      acc1 = MFMA16(Al, b1h, acc1);
    }
  }
  float spv2[4];
#pragma unroll
  for (int j = 0; j < 4; ++j) spv2[j] = spv[j];
  act_only<ACT0>(acc0, spv, sv0);
  if (TWO) act_only<ACT1>(acc1, spv2, sv1);
}

// round A: s0 = h + sigmoid(c)*(tanh(h') - h); A = [x_t | h], K=1024, W0.
__device__ __forceinline__ void roundA(const float *xin, int t, const u16 *Wh, const u16 *Wl,
                                       const u16 *lds, int rt, int cb, int ln, int l4, int l15,
                                       float *sv) {
  float spv[4];
#pragma unroll
  for (int j = 0; j < 4; ++j) spv[j] = lds_elem(lds, l4 * 4 + j, cb * 8 + (l15 >> 1));
  f32x4 acc = {0.f, 0.f, 0.f, 0.f};
  const u16 *wh = Wh + (cb * 32 * 64 + ln) * 8;
  const u16 *wl = Wl + (cb * 32 * 64 + ln) * 8;
  const float *xp = xin + (t * 128 + rt * 16 + l15) * 512 + l4 * 8;
#pragma unroll
  for (int kc = 0; kc < 16; ++kc) {  // x half (k<512), on-the-fly hi/lo split
    f32x4 xa = *(const f32x4 *)(xp + kc * 32);
    f32x4 xb = *(const f32x4 *)(xp + kc * 32 + 4);
    union { u16 u[8]; bf16x8 v; } H, Lo;
#pragma unroll
    for (int e = 0; e < 4; ++e) {
      splitbf(xa[e], H.u[e], Lo.u[e]);
      splitbf(xb[e], H.u[4 + e], Lo.u[4 + e]);
    }
    bf16x8 bh = *(const bf16x8 *)(wh + kc * 512);
    bf16x8 bl = *(const bf16x8 *)(wl + kc * 512);
    acc = MFMA16(H.v, bh, acc);
    acc = MFMA16(H.v, bl, acc);
    acc = MFMA16(Lo.v, bh, acc);
  }
#pragma unroll
  for (int kc = 0; kc < 16; ++kc) {  // h half (k>=512), from staged LDS
    bf16x8 Ah = *(const bf16x8 *)(lds + (kc * 64 + ln) * 8);
    bf16x8 Al = *(const bf16x8 *)(lds + 8192 + (kc * 64 + ln) * 8);
    bf16x8 bh = *(const bf16x8 *)(wh + (16 + kc) * 512);
    bf16x8 bl = *(const bf16x8 *)(wl + (16 + kc) * 512);
    acc = MFMA16(Ah, bh, acc);
    acc = MFMA16(Ah, bl, acc);
    acc = MFMA16(Al, bh, acc);
  }
  act_only<0>(acc, spv, sv);
}

// hierarchical epoch barrier over 256 WGs (8 clusters x 32), bounded polls
__device__ __forceinline__ void gbar(u32 *cnt, u32 &ep, u32 &pb) {
  wait_vm();
  __syncthreads();
  ep += 256u;
  if (threadIdx.x == 0) {
    const int c = blockIdx.x & 7;
    u32 old = __hip_atomic_fetch_add(&cnt[c * 64], 1u, __ATOMIC_RELAXED, __HIP_MEMORY_SCOPE_AGENT);
    if (((old + 1u) & 31u) == 0u)
      __hip_atomic_fetch_add(&cnt[512], 32u, __ATOMIC_RELAXED, __HIP_MEMORY_SCOPE_AGENT);
    bool ok = false;
    for (u32 i = 0; i < pb; ++i) {
      u32 v = __hip_atomic_load(&cnt[512], __ATOMIC_RELAXED, __HIP_MEMORY_SCOPE_AGENT);
      if ((int)(v - ep) >= 0) { ok = true; break; }
      __builtin_amdgcn_s_sleep(2);
    }
    if (!ok) pb = 4096u;
  }
  __syncthreads();
}

__global__ __launch_bounds__(256, 1) void darts_rnn(
    const float *__restrict__ xin, const float *__restrict__ h0in,
    const float *__restrict__ W0, const float *__restrict__ Wsi,
    float *__restrict__ out, u16 *__restrict__ wsu) {
  __shared__ u16 smem[16384];      // 32KB staging panel
  __shared__ float fscr[4][128];   // per-wave transpose scratch
  u32 *cnt = (u32 *)wsu;
  u16 *Wh = wsu + 2048;            // byte 4096
  u16 *Wl = Wh + 5242880;
  u16 *S = Wl + 5242880;

  const int tid = threadIdx.x, bid = blockIdx.x;
  const int ln = tid & 63, wid = tid >> 6;
  const int l15 = ln & 15, l4 = ln >> 4;
  const int rt = (bid & 127) >> 4;
  const int cb = (bid & 15) * 4 + wid;
  float *fscrw = fscr[wid];

  u32 ep = 0, pb = 1u << 22;

  // ---- hygiene: flush dirty ws lines (poison), then invalidate L2 ----
  if (wid == 0) asm volatile("buffer_wbl2 sc1" ::: "memory");
  wait_vm();
  gbar(cnt, ep, pb);
  if (wid == 0) asm volatile("buffer_inv sc1" ::: "memory");
  wait_vm();
  gbar(cnt, ep, pb);

  // ---- P0: weight hi/lo split into fragment layout ----
  for (int idx = bid * 256 + tid; idx < 5242880; idx += 65536) {
    int mk = idx >> 10, oc = idx & 1023;
    int m, k;
    if (mk < 1024) { m = 0; k = mk; } else { m = 1 + ((mk - 1024) >> 9); k = (mk - 1024) & 511; }
    float v = (m == 0) ? W0[k * 1024 + oc] : Wsi[((m - 1) * 512 + k) * 1024 + oc];
    int colp = (oc < 512) ? (oc * 2) : ((oc - 512) * 2 + 1);  // interleave c,h cols
    int cbw = colp >> 4;
    int kc = k >> 5;
    int lnn = (colp & 15) + ((k >> 3) & 3) * 16;
    int el = k & 7;
    int lineBase = (m == 0) ? (cbw * 32 + kc) : (cbw * 16 + kc);  // W0: K=1024
    int e = mbase(m) + (lineBase * 64 + lnn) * 8 + el;
    u16 hi, lo; splitbf(v, hi, lo);
    st16_sc(Wh + e, hi);
    st16_sc(Wl + e, lo);
  }
  {  // h0 -> slot 0
    int g = bid * 256 + tid;         // 65536 = 128*512
    int row = g >> 9, k = g & 511;
    u16 hi, lo; splitbf(h0in[g], hi, lo);
    int o = goff(0, row, k);
    st16_sc(S + o, hi);
    st16_sc(S + o + 8192, lo);
  }
  gbar(cnt, ep, pb);

  for (int t = 0; t < 256; ++t) {
    float rs1[4], rs2[4], rs4[4], rs5[4], dum[4];
    // ---- round A: half0: s0 <- W0 @ [x_t | h] -> slot1 ----
    if (bid < 128) {
      stage_panel(S, 0, rt, smem, tid);
      __syncthreads();
      float sv[4];
      roundA(xin, t, Wh, Wl, smem, rt, cb, ln, l4, l15, sv);
      store_state(sv, S, 1, rt, cb, fscrw, ln, l4, l15);
    }
    gbar(cnt, ep, pb);
    // ---- round B: half0: s1 <- Ws0(sig) on s0 -> slot2, reg rs1 ----
    if (bid < 128) {
      stage_panel(S, 1, rt, smem, tid);
      __syncthreads();
      gemm512<1, 1, false>(Wh, Wl, smem, 1, 1, cb, ln, l4, l15, rs1, dum);
      store_state(rs1, S, 2, rt, cb, fscrw, ln, l4, l15);
    }
    gbar(cnt, ep, pb);
    // ---- round C: A = s1. half0: s2(relu)->slot3+rs2, s4(ident) reg;
    //                        half1: s3(relu)->slot4 ----
    stage_panel(S, 2, rt, smem, tid);
    __syncthreads();
    if (bid < 128) {
      gemm512<2, 3, true>(Wh, Wl, smem, 2, 4, cb, ln, l4, l15, rs2, rs4);
      store_state(rs2, S, 3, rt, cb, fscrw, ln, l4, l15);
    } else {
      float sv[4];
      gemm512<2, 2, false>(Wh, Wl, smem, 3, 3, cb, ln, l4, l15, sv, dum);
      store_state(sv, S, 4, rt, cb, fscrw, ln, l4, l15);
    }
    gbar(cnt, ep, pb);
    // ---- round D: half0: s5(tanh) on s2 -> slot5+rs5; half1: s7 on s3 -> slot6 ----
    stage_panel(S, (bid < 128) ? 3 : 4, rt, smem, tid);
    __syncthreads();
    if (bid < 128) {
      gemm512<0, 0, false>(Wh, Wl, smem, 5, 5, cb, ln, l4, l15, rs5, dum);
      store_state(rs5, S, 5, rt, cb, fscrw, ln, l4, l15);
    } else {
      float sv[4];
      gemm512<0, 0, false>(Wh, Wl, smem, 7, 7, cb, ln, l4, l15, sv, dum);
      store_state(sv, S, 6, rt, cb, fscrw, ln, l4, l15);
    }
    gbar(cnt, ep, pb);
    // ---- round E: half0: s6(sig),s8(relu) on s5; mean -> out, h -> slot0 ----
    if (bid < 128) {
      u16x8 p3h, p3l, p7h, p7l;
      if (ln < 16) {  // prefetch s3,s7 row-slices; latency hides under stage+gemm
        const u16 *p3 = S + goff(4, rt * 16 + ln, cb * 8);
        const u16 *p7 = S + goff(6, rt * 16 + ln, cb * 8);
        issue_ld128u_sc(p3h, p3);
        issue_ld128u_sc(p3l, p3 + 8192);
        issue_ld128u_sc(p7h, p7);
        issue_ld128u_sc(p7l, p7 + 8192);
      }
      stage_panel(S, 5, rt, smem, tid);   // wait_vm inside covers prefetch
      __syncthreads();
      float sv6[4], sv8[4];
      gemm512<1, 2, true>(Wh, Wl, smem, 6, 8, cb, ln, l4, l15, sv6, sv8);
      if ((l15 & 1) == 0) {
#pragma unroll
        for (int j = 0; j < 4; ++j)
          fscrw[(l4 * 4 + j) * 8 + (l15 >> 1)] = rs1[j] + rs2[j] + rs4[j] + rs5[j] + sv6[j] + sv8[j];
      }
      if (ln < 16) {
        float o0[8];
        u16x8 H, L;
#pragma unroll
        for (int c = 0; c < 8; ++c) {
          float v = fscrw[ln * 8 + c];
          v += bf2f(p3h[c]) + bf2f(p3l[c]);
          v += bf2f(p7h[c]) + bf2f(p7l[c]);
          float hnew = v * 0.125f;
          o0[c] = hnew;
          u16 hi, lo; splitbf(hnew, hi, lo);
          H[c] = hi; L[c] = lo;
        }
        int row = rt * 16 + ln;
        float *op = out + t * 65536 + row * 512 + cb * 8;
        *(f32x4 *)op = *(f32x4 *)&o0[0];
        *(f32x4 *)(op + 4) = *(f32x4 *)&o0[4];
        if (t == 255) {
          float *op2 = out + 16777216 + row * 512 + cb * 8;
          *(f32x4 *)op2 = *(f32x4 *)&o0[0];
          *(f32x4 *)(op2 + 4) = *(f32x4 *)&o0[4];
        }
        u16 *p = S + goff(0, row, cb * 8);
        st128_sc(p, H);
        st128_sc(p + 8192, L);
      }
    }
    gbar(cnt, ep, pb);
  }
}

extern "C" void kernel_launch(void *const *d_in, const int *in_sizes, int n_in,
                              void *d_out, int out_size, void *d_ws, size_t ws_size,
                              hipStream_t stream) {
  const float *x = (const float *)d_in[0];
  const float *h0 = (const float *)d_in[1];
  const float *W0 = (const float *)d_in[2];
  const float *Ws = (const float *)d_in[3];
  float *out = (float *)d_out;
  u16 *ws = (u16 *)d_ws;

  hipMemsetAsync(d_ws, 0, 4096, stream);  // zero barrier counters

  void *args[] = {(void *)&x, (void *)&h0, (void *)&W0, (void *)&Ws, (void *)&out, (void *)&ws};
  hipError_t err = hipLaunchCooperativeKernel((void *)darts_rnn, dim3(256), dim3(256),
                                              args, 0, stream);
  if (err != hipSuccess) {
    (void)hipGetLastError();
    darts_rnn<<<dim3(256), dim3(256), 0, stream>>>(x, h0, W0, Ws, out, ws);
  }
}